// Round 13
// baseline (885.228 us; speedup 1.0000x reference)
//
#include <hip/hip_runtime.h>
#include <hip/hip_bf16.h>
#include <cmath>

#define TT 512
#define BB 32
#define EE 256
#define HH 128
#define KCRF 12
#define NEGF (-10000.0f)

// ---------------------------------------------------------------------------
// K12 fused, XCD-partitioned. 256 WGs x 512 threads.
//   blockIdx%8 in {0,1}  -> scan WG (64 total) => XCD 0-1 exclusively
//                           (assuming round-robin blockIdx->XCD; if the
//                           mapping differs this only costs speed).
//   blockIdx%8 in {2..7} -> producer WG (192)  => XCD 2-7.
// R12 lesson: mixed placement put 24 streaming producers on every scan XCD;
// producer traffic (70MB reads + 67MB XG writes) thrashed the L2s serving
// the scan. Partition isolates them. Producers store XG nontemporally (write-
// once data, read only by remote XCDs via L3). Flag protocol unchanged from
// R12 (correctness-proven): __syncthreads drains stores -> tid0 __threadfence
// -> device atomicAdd; consumers burst-poll once per 32 steps (18 lanes).
// ---------------------------------------------------------------------------
__global__ __launch_bounds__(512)
void k12_fused(const int* __restrict__ sent, const float* __restrict__ embed,
               const float* __restrict__ Wf, const float* __restrict__ bfv,
               const float* __restrict__ Wr, const float* __restrict__ brv,
               const float* __restrict__ Whf, const float* __restrict__ Whr,
               const float* __restrict__ h0, const float* __restrict__ c0,
               float* XG, float* __restrict__ HS, int* flags)
{
  __shared__ __align__(16) float As[64][36];
  __shared__ __align__(16) float Bs[256][36];
  __shared__ __align__(16) float hs[128];
  __shared__ float gs[512];

  const int wg = blockIdx.x;
  const int tid = threadIdx.x;
  const int xslot = wg & 7;

  if (xslot >= 2) {
    // ------------------------- producers (XCD 2-7) -------------------------
    const int prod = (wg >> 3) * 6 + (xslot - 2);   // 0..191
    const int sub = tid >> 8;            // 0/1: which 128-col half of slab
    const int t256 = tid & 255;
    const int ty = t256 >> 4, tx = t256 & 15;
    for (int item = prod; item < 1024; item += 192) {
      const int g = item >> 2, q = item & 3;
      const int pair = (q < 2) ? g : (255 - g);     // t-pair (64 rows)
      const int half = q >> 1;                      // 0: cols 0-511, 1: 512+
      const int n0 = (q & 1) * 256 + half * 512;    // slab base (256 cols)
      const int m0 = pair * 64;
      const int colbase = n0 + sub * 128;

      float acc[4][8];
#pragma unroll
      for (int i = 0; i < 4; ++i)
#pragma unroll
        for (int j = 0; j < 8; ++j) acc[i][j] = 0.f;

      for (int k0 = 0; k0 < 256; k0 += 32) {
        { // A: 64x32 gathered embed rows, 1 float4/thread
          int row = tid >> 3, c4 = (tid & 7) << 2;
          int R = m0 + row, t = R >> 5, b = R & 31;
          *(float4*)&As[row][c4] =
              *(const float4*)(embed + (long)sent[b * TT + t] * 256 + k0 + c4);
        }
#pragma unroll
        for (int r = 0; r < 4; ++r) {   // B: 256x32 of W_cat
          int idx = tid + r * 512, row = idx >> 3, c4 = (idx & 7) << 2;
          int col = n0 + row;
          const float* src = (col < 512) ? (Wf + (long)col * 256)
                                         : (Wr + (long)(col - 512) * 256);
          *(float4*)&Bs[row][c4] = *(const float4*)(src + k0 + c4);
        }
        __syncthreads();
#pragma unroll
        for (int kk = 0; kk < 32; ++kk) {
          float a[4], bv[8];
#pragma unroll
          for (int i = 0; i < 4; ++i) a[i] = As[ty * 4 + i][kk];
#pragma unroll
          for (int j = 0; j < 8; ++j) bv[j] = Bs[sub * 128 + tx + 16 * j][kk];
#pragma unroll
          for (int i = 0; i < 4; ++i)
#pragma unroll
            for (int j = 0; j < 8; ++j) acc[i][j] = fmaf(a[i], bv[j], acc[i][j]);
        }
        __syncthreads();
      }
#pragma unroll
      for (int i = 0; i < 4; ++i) {
        const long R = m0 + ty * 4 + i;
#pragma unroll
        for (int j = 0; j < 8; ++j) {
          const int col = colbase + tx + 16 * j;
          const float bias = (col < 512) ? bfv[col] : brv[col - 512];
          __builtin_nontemporal_store(acc[i][j] + bias, &XG[R * 1024 + col]);
        }
      }
      __syncthreads();   // drains vmcnt(0): all threads' XG stores complete
      if (tid == 0) { __threadfence(); atomicAdd(&flags[pair * 2 + half], 1); }
    }
  } else {
    // -------------- scan (XCD 0-1; round-3 anchor + burst waits) -----------
    const int scan_id = (wg >> 3) * 2 + xslot;      // 0..63
    const int dir = scan_id >> 5;
    const int b = scan_id & 31;
    const int j = tid;
    const float* Wh = dir ? Whr : Whf;

    float4 w[32];
#pragma unroll
    for (int i = 0; i < 32; ++i)
      w[i] = *(const float4*)(Wh + (long)j * 128 + i * 4);

    float c = 0.f;
    if (j < 128) {
      hs[j] = h0[(dir * 32 + b) * 128 + j];
      c = c0[(dir * 32 + b) * 128 + j];
    }
    __syncthreads();

    const int t0 = dir ? (TT - 1) : 0;
    const long stepoff = dir ? -32768 : 32768;   // 32*1024 floats per t
    const float* xp = XG + ((long)t0 * 32 + b) * 1024 + dir * 512 + j;
    const int gate = j >> 7;   // 0=i 1=f 2=g 3=o

    // burst wait: lanes 0..17 poll the 18 t-pairs covering the next 32 steps
    // (incl. the one-step prefetch).
    {
      if (tid < 18) {
        int p0 = dir ? ((TT - 1) >> 1) : 0;
        int p = dir ? (p0 - tid) : (p0 + tid);
        p = p < 0 ? 0 : (p > 255 ? 255 : p);
        while (atomicAdd(&flags[p * 2 + dir], 0) < 2) __builtin_amdgcn_s_sleep(8);
      }
      __syncthreads();
    }
    float xg_cur = *xp;

    for (int s = 0; s < TT; ++s) {
      if ((s & 31) == 0 && s) {
        if (tid < 18) {
          int p0 = (dir ? (TT - 1 - s) : s) >> 1;
          int p = dir ? (p0 - tid) : (p0 + tid);
          p = p < 0 ? 0 : (p > 255 ? 255 : p);
          while (atomicAdd(&flags[p * 2 + dir], 0) < 2) __builtin_amdgcn_s_sleep(8);
        }
        __syncthreads();
      }
      const int t = dir ? (TT - 1 - s) : s;
      float xg_nxt = 0.f;
      if (s + 1 < TT) { xp += stepoff; xg_nxt = *xp; }

      float a0 = xg_cur, a1 = 0.f, a2 = 0.f, a3 = 0.f;
#pragma unroll
      for (int i = 0; i < 32; ++i) {
        const float4 hv = *(const float4*)(hs + 4 * i);   // uniform broadcast
        a0 = fmaf(w[i].x, hv.x, a0);
        a1 = fmaf(w[i].y, hv.y, a1);
        a2 = fmaf(w[i].z, hv.z, a2);
        a3 = fmaf(w[i].w, hv.w, a3);
      }
      const float acc = (a0 + a1) + (a2 + a3);
      const float act = (gate == 2) ? tanhf(acc) : (1.f / (1.f + expf(-acc)));
      gs[j] = act;
      __syncthreads();           // gs ready; all reads of hs complete
      if (j < 128) {
        float ig = gs[j], fg = gs[128 + j], gg = gs[256 + j], og = gs[384 + j];
        c = fmaf(fg, c, ig * gg);
        float h = og * tanhf(c);
        hs[j] = h;
        HS[((long)t * 32 + b) * 256 + dir * 128 + j] = h;
      }
      __syncthreads();           // hs ready for next step
      xg_cur = xg_nxt;
    }
  }
}

// ---------------------------------------------------------------------------
// K3: feats. FE layout [t][k][b]. (unchanged)
// ---------------------------------------------------------------------------
__global__ __launch_bounds__(64) void k3_feats(const float* __restrict__ HS,
    const float* __restrict__ Wout, const float* __restrict__ bout,
    float* __restrict__ FE)
{
  __shared__ __align__(16) float ws[12 * 256];
  __shared__ float bs[12];
  const int tid = threadIdx.x;
  for (int i = tid; i < 768; i += 64)
    ((float4*)ws)[i] = ((const float4*)Wout)[i];
  if (tid < 12) bs[tid] = bout[tid];
  __syncthreads();
  const long row = (long)blockIdx.x * 64 + tid;
  const float4* hp = (const float4*)(HS + row * 256);
  float acc[12];
#pragma unroll
  for (int k = 0; k < 12; ++k) acc[k] = bs[k];
  for (int e4 = 0; e4 < 64; ++e4) {
    float4 hv = hp[e4];
#pragma unroll
    for (int k = 0; k < 12; ++k) {
      const float4 wv = *(const float4*)&ws[k * 256 + e4 * 4];
      acc[k] = fmaf(hv.x, wv.x, acc[k]);
      acc[k] = fmaf(hv.y, wv.y, acc[k]);
      acc[k] = fmaf(hv.z, wv.z, acc[k]);
      acc[k] = fmaf(hv.w, wv.w, acc[k]);
    }
  }
  const int t = (int)(row >> 5), b = (int)(row & 31);
#pragma unroll
  for (int k = 0; k < 12; ++k) FE[((long)t * 12 + k) * 32 + b] = acc[k];
}

// ---------------------------------------------------------------------------
// K4: Viterbi, single-wave WGs (unchanged from round 11 -- proven).
// ---------------------------------------------------------------------------
__global__ __launch_bounds__(64) void k4_viterbi(const float* __restrict__ FE,
    const float* __restrict__ trans, int* __restrict__ out)
{
  __shared__ unsigned char ptrl[TT * 48];       // [t][bsub][12]  24576 B
  __shared__ __align__(16) float sc[2][4][12];  // double-buffered scores
  const int l = threadIdx.x;
  const int bsub = l / 12;                      // 0..5; active if <4
  const int nxt = l % 12;
  const bool act = (bsub < 4);
  const int bs = act ? bsub : 0;                // clamped for reads
  const int b = blockIdx.x * 4 + bs;

  float tr[12], stopv[12];
#pragma unroll
  for (int p = 0; p < 12; ++p) tr[p] = trans[nxt * 12 + p];
#pragma unroll
  for (int p = 0; p < 12; ++p) stopv[p] = trans[10 * 12 + p];   // STOP=10

  if (act) sc[0][bsub][nxt] = (nxt == 9) ? 0.f : NEGF;          // START=9
  __syncthreads();

  float fnext = FE[nxt * 32 + b];
  for (int t = 0; t < TT; ++t) {
    const int cur = t & 1;
    const float feat = fnext;
    if (t + 1 < TT) fnext = FE[((t + 1) * 12 + nxt) * 32 + b];

    float sp[12];
    *(float4*)&sp[0] = *(const float4*)&sc[cur][bs][0];
    *(float4*)&sp[4] = *(const float4*)&sc[cur][bs][4];
    *(float4*)&sp[8] = *(const float4*)&sc[cur][bs][8];
    float best = -1e30f; int arg = 0;
#pragma unroll
    for (int p = 0; p < 12; ++p) {
      const float v = sp[p] + tr[p];
      if (v > best) { best = v; arg = p; }
    }
    if (act) {
      sc[cur ^ 1][bsub][nxt] = best + feat;     // write other buffer: no WAR
      ptrl[t * 48 + bsub * 12 + nxt] = (unsigned char)arg;
    }
    __syncthreads();                            // single wave: near-free
  }

  float best = -1e30f; int arg = 0;
#pragma unroll
  for (int p = 0; p < 12; ++p) {
    const float v = sc[0][bs][p] + stopv[p];
    if (v > best) { best = v; arg = p; }
  }
  if (act && nxt == 0) {
    int tag = arg;
    for (int t = TT - 1; t >= 0; --t) {
      out[b * TT + t] = tag;
      if (t) tag = ptrl[t * 48 + bsub * 12 + tag];
    }
  }
}

// ---------------------------------------------------------------------------
extern "C" void kernel_launch(void* const* d_in, const int* in_sizes, int n_in,
                              void* d_out, int out_size, void* d_ws, size_t ws_size,
                              hipStream_t stream)
{
  const int* sent = (const int*)d_in[0];
  const float* h0 = (const float*)d_in[1];
  const float* c0 = (const float*)d_in[2];
  const float* embed = (const float*)d_in[3];
  const float* Wif = (const float*)d_in[4];
  const float* Whf = (const float*)d_in[5];
  const float* bf = (const float*)d_in[6];
  const float* Wir = (const float*)d_in[7];
  const float* Whr = (const float*)d_in[8];
  const float* br = (const float*)d_in[9];
  const float* Wout = (const float*)d_in[10];
  const float* bout = (const float*)d_in[11];
  const float* trans = (const float*)d_in[12];

  char* ws = (char*)d_ws;
  float* XG = (float*)ws;                                   // 67,108,864 B
  float* HS = (float*)(ws + 67108864);                      // 16,777,216 B
  float* FE = (float*)(ws + 67108864 + 16777216);           //    786,432 B
  int* flags = (int*)(ws + 67108864 + 16777216 + 786432);   //      2,048 B
  int* out = (int*)d_out;

  // flags must be zero every call (harness poisons ws once, never restores)
  hipMemsetAsync(flags, 0, 512 * sizeof(int), stream);

  hipLaunchKernelGGL(k12_fused, dim3(256), dim3(512), 0, stream,
                     sent, embed, Wif, bf, Wir, br, Whf, Whr, h0, c0,
                     XG, HS, flags);
  hipLaunchKernelGGL(k3_feats, dim3(256), dim3(64), 0, stream,
                     HS, Wout, bout, FE);
  hipLaunchKernelGGL(k4_viterbi, dim3(8), dim3(64), 0, stream,
                     FE, trans, out);
}

// Round 14
// 779.146 us; speedup vs baseline: 1.1362x; 1.1362x over previous
//
#include <hip/hip_runtime.h>
#include <hip/hip_bf16.h>
#include <cmath>

#define TT 512
#define BB 32
#define EE 256
#define HH 128
#define KCRF 12
#define NEGF (-10000.0f)

// ---------------------------------------------------------------------------
// K1: XG[row=t*32+b][col 0..1023] = embed[sent[b,t]] . W_cat[col]^T + bias
// Round-1..9 proven version (4x8 micro, 64x128 tile, 2048 blocks).
// R10's 8x8 rewrite regressed (register pressure killed latency hiding);
// R12/R13's producer-consumer fusion regressed twice (warmup + XCD-L2
// interference > overlap gain). This is the keeper.
// ---------------------------------------------------------------------------
__global__ __launch_bounds__(256) void k1_xg(const int* __restrict__ sent,
    const float* __restrict__ embed,
    const float* __restrict__ Wf, const float* __restrict__ bf,
    const float* __restrict__ Wr, const float* __restrict__ br,
    float* __restrict__ XG)
{
  __shared__ __align__(16) float As[64][36];
  __shared__ __align__(16) float Bs[128][36];
  const int tid = threadIdx.x;
  const int m0 = (blockIdx.x >> 3) * 64;
  const int n0 = (blockIdx.x & 7) * 128;
  const int ty = tid >> 4, tx = tid & 15;
  float acc[4][8];
#pragma unroll
  for (int i = 0; i < 4; ++i)
#pragma unroll
    for (int j = 0; j < 8; ++j) acc[i][j] = 0.f;

  for (int k0 = 0; k0 < 256; k0 += 32) {
#pragma unroll
    for (int r = 0; r < 2; ++r) {
      int idx = tid + r * 256;
      int row = idx >> 3;
      int c4 = (idx & 7) << 2;
      int R = m0 + row;
      int t = R >> 5, b = R & 31;
      const float4 v = *(const float4*)(embed + (long)sent[b * TT + t] * 256 + k0 + c4);
      *(float4*)&As[row][c4] = v;
    }
#pragma unroll
    for (int r = 0; r < 4; ++r) {
      int idx = tid + r * 256;
      int row = idx >> 3;
      int c4 = (idx & 7) << 2;
      int col = n0 + row;
      const float* src = (col < 512) ? (Wf + (long)col * 256) : (Wr + (long)(col - 512) * 256);
      const float4 v = *(const float4*)(src + k0 + c4);
      *(float4*)&Bs[row][c4] = v;
    }
    __syncthreads();
#pragma unroll
    for (int kk = 0; kk < 32; ++kk) {
      float a[4], bv[8];
#pragma unroll
      for (int i = 0; i < 4; ++i) a[i] = As[ty * 4 + i][kk];
#pragma unroll
      for (int j = 0; j < 8; ++j) bv[j] = Bs[tx + 16 * j][kk];
#pragma unroll
      for (int i = 0; i < 4; ++i)
#pragma unroll
        for (int j = 0; j < 8; ++j) acc[i][j] = fmaf(a[i], bv[j], acc[i][j]);
    }
    __syncthreads();
  }
#pragma unroll
  for (int i = 0; i < 4; ++i) {
    int R = m0 + ty * 4 + i;
#pragma unroll
    for (int j = 0; j < 8; ++j) {
      int col = n0 + tx + 16 * j;
      float bias = (col < 512) ? bf[col] : br[col - 512];
      XG[(long)R * 1024 + col] = acc[i][j] + bias;
    }
  }
}

// ---------------------------------------------------------------------------
// K2: LSTM scans -- UNCHANGED anchor (471us, VGPR 80 / SGPR 48, zero bank
// conflicts, reproduced 5x). Floor of the LDS-broadcast design family:
// per chain-step LDS must deliver 512 threads x 128 h x 4B = 256KB on one
// CU (~2048cy). All redesigns falsified: readlane (R2/R5), fewer waves
// (R6/R7), split-K (R4), batch-pairing (R8), fusion (R12/R13). Do not touch.
// ---------------------------------------------------------------------------
__global__ __launch_bounds__(512) __attribute__((amdgpu_waves_per_eu(1)))
void k2_scan(const float* __restrict__ XG,
    const float* __restrict__ Whf, const float* __restrict__ Whr,
    const float* __restrict__ h0, const float* __restrict__ c0,
    float* __restrict__ HS)
{
  const int wg = blockIdx.x;
  const int dir = wg >> 5;
  const int b = wg & 31;
  const int j = threadIdx.x;
  const float* Wh = dir ? Whr : Whf;

  float4 w[32];
#pragma unroll
  for (int i = 0; i < 32; ++i)
    w[i] = *(const float4*)(Wh + (long)j * 128 + i * 4);

  __shared__ __align__(16) float hs[128];
  __shared__ float gs[512];
  float c = 0.f;
  if (j < 128) {
    hs[j] = h0[(dir * 32 + b) * 128 + j];
    c = c0[(dir * 32 + b) * 128 + j];
  }
  __syncthreads();

  const int t0 = dir ? (TT - 1) : 0;
  const long stepoff = dir ? -32768 : 32768;   // 32*1024 floats per t
  const float* xp = XG + ((long)t0 * 32 + b) * 1024 + dir * 512 + j;
  float xg_cur = *xp;
  const int gate = j >> 7;   // 0=i 1=f 2=g 3=o

  for (int s = 0; s < TT; ++s) {
    const int t = dir ? (TT - 1 - s) : s;
    float xg_nxt = 0.f;
    if (s + 1 < TT) { xp += stepoff; xg_nxt = *xp; }

    float a0 = xg_cur, a1 = 0.f, a2 = 0.f, a3 = 0.f;
#pragma unroll
    for (int i = 0; i < 32; ++i) {
      const float4 hv = *(const float4*)(hs + 4 * i);   // uniform -> broadcast
      a0 = fmaf(w[i].x, hv.x, a0);
      a1 = fmaf(w[i].y, hv.y, a1);
      a2 = fmaf(w[i].z, hv.z, a2);
      a3 = fmaf(w[i].w, hv.w, a3);
    }
    const float acc = (a0 + a1) + (a2 + a3);
    const float act = (gate == 2) ? tanhf(acc) : (1.f / (1.f + expf(-acc)));
    gs[j] = act;
    __syncthreads();           // gs ready; all reads of hs complete
    if (j < 128) {
      float ig = gs[j], fg = gs[128 + j], gg = gs[256 + j], og = gs[384 + j];
      c = fmaf(fg, c, ig * gg);
      float h = og * tanhf(c);
      hs[j] = h;
      HS[((long)t * 32 + b) * 256 + dir * 128 + j] = h;
    }
    __syncthreads();           // hs ready for next step
    xg_cur = xg_nxt;
  }
}

// ---------------------------------------------------------------------------
// K3: feats. FE layout [t][k][b]. (unchanged)
// ---------------------------------------------------------------------------
__global__ __launch_bounds__(64) void k3_feats(const float* __restrict__ HS,
    const float* __restrict__ Wout, const float* __restrict__ bout,
    float* __restrict__ FE)
{
  __shared__ __align__(16) float ws[12 * 256];
  __shared__ float bs[12];
  const int tid = threadIdx.x;
  for (int i = tid; i < 768; i += 64)
    ((float4*)ws)[i] = ((const float4*)Wout)[i];
  if (tid < 12) bs[tid] = bout[tid];
  __syncthreads();
  const long row = (long)blockIdx.x * 64 + tid;
  const float4* hp = (const float4*)(HS + row * 256);
  float acc[12];
#pragma unroll
  for (int k = 0; k < 12; ++k) acc[k] = bs[k];
  for (int e4 = 0; e4 < 64; ++e4) {
    float4 hv = hp[e4];
#pragma unroll
    for (int k = 0; k < 12; ++k) {
      const float4 wv = *(const float4*)&ws[k * 256 + e4 * 4];
      acc[k] = fmaf(hv.x, wv.x, acc[k]);
      acc[k] = fmaf(hv.y, wv.y, acc[k]);
      acc[k] = fmaf(hv.z, wv.z, acc[k]);
      acc[k] = fmaf(hv.w, wv.w, acc[k]);
    }
  }
  const int t = (int)(row >> 5), b = (int)(row & 31);
#pragma unroll
  for (int k = 0; k < 12; ++k) FE[((long)t * 12 + k) * 32 + b] = acc[k];
}

// ---------------------------------------------------------------------------
// K4: Viterbi, single-wave WGs (round-11 proven: rest-of-pipeline 338->309).
// 8 WGs x 64 threads; WG handles 4 batches; lane = bsub*12 + nxt. Scores in
// sc[2][4][12] LDS read as 3 aligned b128 (conflict-free); one single-wave
// barrier/step; pointers as bytes in per-WG LDS; backtrace parallel across
// 8 CUs. Strict > ascending p == jnp.argmax first-max semantics.
// ---------------------------------------------------------------------------
__global__ __launch_bounds__(64) void k4_viterbi(const float* __restrict__ FE,
    const float* __restrict__ trans, int* __restrict__ out)
{
  __shared__ unsigned char ptrl[TT * 48];       // [t][bsub][12]  24576 B
  __shared__ __align__(16) float sc[2][4][12];  // double-buffered scores
  const int l = threadIdx.x;
  const int bsub = l / 12;                      // 0..5; active if <4
  const int nxt = l % 12;
  const bool act = (bsub < 4);
  const int bs = act ? bsub : 0;                // clamped for reads
  const int b = blockIdx.x * 4 + bs;

  float tr[12], stopv[12];
#pragma unroll
  for (int p = 0; p < 12; ++p) tr[p] = trans[nxt * 12 + p];
#pragma unroll
  for (int p = 0; p < 12; ++p) stopv[p] = trans[10 * 12 + p];   // STOP=10

  if (act) sc[0][bsub][nxt] = (nxt == 9) ? 0.f : NEGF;          // START=9
  __syncthreads();

  float fnext = FE[nxt * 32 + b];
  for (int t = 0; t < TT; ++t) {
    const int cur = t & 1;
    const float feat = fnext;
    if (t + 1 < TT) fnext = FE[((t + 1) * 12 + nxt) * 32 + b];

    float sp[12];
    *(float4*)&sp[0] = *(const float4*)&sc[cur][bs][0];
    *(float4*)&sp[4] = *(const float4*)&sc[cur][bs][4];
    *(float4*)&sp[8] = *(const float4*)&sc[cur][bs][8];
    float best = -1e30f; int arg = 0;
#pragma unroll
    for (int p = 0; p < 12; ++p) {
      const float v = sp[p] + tr[p];
      if (v > best) { best = v; arg = p; }
    }
    if (act) {
      sc[cur ^ 1][bsub][nxt] = best + feat;     // write other buffer: no WAR
      ptrl[t * 48 + bsub * 12 + nxt] = (unsigned char)arg;
    }
    __syncthreads();                            // single wave: near-free
  }

  float best = -1e30f; int arg = 0;
#pragma unroll
  for (int p = 0; p < 12; ++p) {
    const float v = sc[0][bs][p] + stopv[p];
    if (v > best) { best = v; arg = p; }
  }
  if (act && nxt == 0) {
    int tag = arg;
    for (int t = TT - 1; t >= 0; --t) {
      out[b * TT + t] = tag;
      if (t) tag = ptrl[t * 48 + bsub * 12 + tag];
    }
  }
}

// ---------------------------------------------------------------------------
extern "C" void kernel_launch(void* const* d_in, const int* in_sizes, int n_in,
                              void* d_out, int out_size, void* d_ws, size_t ws_size,
                              hipStream_t stream)
{
  const int* sent = (const int*)d_in[0];
  const float* h0 = (const float*)d_in[1];
  const float* c0 = (const float*)d_in[2];
  const float* embed = (const float*)d_in[3];
  const float* Wif = (const float*)d_in[4];
  const float* Whf = (const float*)d_in[5];
  const float* bf = (const float*)d_in[6];
  const float* Wir = (const float*)d_in[7];
  const float* Whr = (const float*)d_in[8];
  const float* br = (const float*)d_in[9];
  const float* Wout = (const float*)d_in[10];
  const float* bout = (const float*)d_in[11];
  const float* trans = (const float*)d_in[12];

  char* ws = (char*)d_ws;
  float* XG = (float*)ws;                                   // 67,108,864 B
  float* HS = (float*)(ws + 67108864);                      // 16,777,216 B
  float* FE = (float*)(ws + 67108864 + 16777216);           //    786,432 B
  int* out = (int*)d_out;

  hipLaunchKernelGGL(k1_xg, dim3(2048), dim3(256), 0, stream,
                     sent, embed, Wif, bf, Wir, br, XG);
  hipLaunchKernelGGL(k2_scan, dim3(64), dim3(512), 0, stream,
                     XG, Whf, Whr, h0, c0, HS);
  hipLaunchKernelGGL(k3_feats, dim3(256), dim3(64), 0, stream,
                     HS, Wout, bout, FE);
  hipLaunchKernelGGL(k4_viterbi, dim3(8), dim3(64), 0, stream,
                     FE, trans, out);
}